// Round 18
// baseline (134.484 us; speedup 1.0000x reference)
//
#include <hip/hip_runtime.h>
#include <hip/hip_bf16.h>
#include <stdint.h>

// MHA forward, B=2 S=2048 D=1024 H=16 depth=64.
// Stage 0: prep — W->bf16 transposed Wt[n][k] ONLY
// Stage 1: QKV proj: BM=64 (grid 1536 -> 5 blk/CU). A = raw fp32 x staged via
//          global_load_lds (fp32 LDS tile, bf16 cvt on fragment read);
//          B = bf16 Wt via global_load_lds + XOR swizzle.
// Stage 2: flash attention QBLK=128/KVBLK=128 two-half (R16, frozen)
// Stage 3: output projection (BM=64, R13)

typedef __attribute__((ext_vector_type(8))) short bf16x8;
typedef __attribute__((ext_vector_type(4))) float f32x4;

#define MFMA16(a, b, c) __builtin_amdgcn_mfma_f32_16x16x32_bf16((a), (b), (c), 0, 0, 0)
#define EXP2(x) __builtin_amdgcn_exp2f(x)   // v_exp_f32 (2^x native)

static constexpr int S_LEN = 2048;
static constexpr int DM    = 1024;
static constexpr int DEPTH = 64;
static constexpr float QSCALE = 0.125f * 1.44269504088896340736f;  // 1/sqrt(64)*log2e

__device__ __forceinline__ unsigned short f2b(float f) {
  unsigned u = __float_as_uint(f);
  unsigned r = 0x7FFFu + ((u >> 16) & 1u);   // RNE
  return (unsigned short)((u + r) >> 16);
}

// native bf16 convert (compiler emits/fuses v_cvt_pk_bf16_f32)
__device__ __forceinline__ unsigned short b16(float f) {
  __hip_bfloat16 h = __float2bfloat16(f);
  union { __hip_bfloat16 h; unsigned short u; } c; c.h = h; return c.u;
}

// async global->LDS, 16B per lane; LDS dest must be lane-linear within wave.
__device__ __forceinline__ void gload16(const void* g, void* l) {
  __builtin_amdgcn_global_load_lds(
      (const __attribute__((address_space(1))) void*)g,
      (__attribute__((address_space(3))) void*)l, 16, 0, 0);
}

// Wave-level LDS ordering fence for intra-wave cross-lane exchange.
__device__ __forceinline__ void wave_lds_fence() {
  asm volatile("" ::: "memory");
  __builtin_amdgcn_sched_barrier(0);
}

// ---------------------------------------------------------------------------
// prep: Wt[w][n][k] = bf16(W[k][n]) for w in {q,k,v,o}. 64x64 LDS-tiled.
// ---------------------------------------------------------------------------
__global__ __launch_bounds__(256) void prep_k(
    const float* __restrict__ Wq, const float* __restrict__ Wk,
    const float* __restrict__ Wv, const float* __restrict__ Wo,
    unsigned short* __restrict__ Wt) {
  __shared__ unsigned short ts[64][68];
  const int bid = blockIdx.x;
  const int tid = threadIdx.x;
  const int w = bid >> 8, tile = bid & 255;
  const int tr = tile >> 4, tc = tile & 15;       // tr: k-tile, tc: n-tile
  const float* W = (w == 0) ? Wq : (w == 1) ? Wk : (w == 2) ? Wv : Wo;
  unsigned short* T = Wt + (size_t)w * DM * DM;
  const int kr = tid >> 4, nc = (tid & 15) * 4;
  #pragma unroll
  for (int j = 0; j < 4; ++j) {
    int k = tr * 64 + kr + j * 16;
    float4 v = *(const float4*)&W[(size_t)k * DM + tc * 64 + nc];
    ushort4 u; u.x = f2b(v.x); u.y = f2b(v.y); u.z = f2b(v.z); u.w = f2b(v.w);
    *(ushort4*)&ts[kr + j * 16][nc] = u;
  }
  __syncthreads();
  const int nr = tid >> 4, kc = (tid & 15) * 4;
  #pragma unroll
  for (int j = 0; j < 4; ++j) {
    int n = tc * 64 + nr + j * 16;
    ushort4 u;
    u.x = ts[kc + 0][nr + j * 16];
    u.y = ts[kc + 1][nr + j * 16];
    u.z = ts[kc + 2][nr + j * 16];
    u.w = ts[kc + 3][nr + j * 16];
    *(ushort4*)&T[(size_t)n * DM + tr * 64 + kc] = u;
  }
}

// ---------------------------------------------------------------------------
// QKV projection: C = x_z * Wt_z^T + bias_z. BM=64 x BN=128, BK=32, 4 waves
// (2x2, 32x64 each). A: fp32 via global_load_lds into f32 tile (8 slots/row,
// slot ^= row&7), bf16 cvt on fragment read. B: bf16 Wt via global_load_lds.
// LDS 32KB -> 5 blocks/CU (grid 1536 = 6/CU requested, LDS caps at 5).
// ---------------------------------------------------------------------------
__global__ __launch_bounds__(256, 5) void proj_qkv_k(
    const float* __restrict__ xq, const float* __restrict__ xk,
    const float* __restrict__ xv, const unsigned short* __restrict__ Wt,
    const float* __restrict__ bq, const float* __restrict__ bk, const float* __restrict__ bv,
    unsigned short* __restrict__ Qh, unsigned short* __restrict__ Kh,
    unsigned short* __restrict__ Vt) {
  __shared__ __align__(16) float Asf[2][64][32];
  __shared__ __align__(16) unsigned short Bs[2][128][32];

  const int z = blockIdx.z;
  const float* A32 = (z == 0) ? xq : (z == 1) ? xk : xv;
  const unsigned short* Bt = Wt + (size_t)z * DM * DM;
  const float* bias = (z == 0) ? bq : (z == 1) ? bk : bv;
  const float scale = (z == 0) ? QSCALE : 1.0f;
  unsigned short* O = (z == 0) ? Qh : (z == 1) ? Kh : Vt;

  const int bm = blockIdx.x, bn = blockIdx.y;
  const int tid = threadIdx.x;
  const int wave = tid >> 6, lane = tid & 63;
  const int wr = wave >> 1, wc = wave & 1;
  const int g = lane >> 4, i16 = lane & 15;
  const int arow = tid >> 3, aslot = tid & 7;     // A: 64 rows x 8 slots /2
  const int brow = tid >> 2, bslot = tid & 3;     // B: 128 rows x 4 slots /2

  f32x4 acc[2][4] = {};

  auto stage = [&](int ks, int buf) {
    // A: 512 slot-units / 256 threads = 2 gloads
    #pragma unroll
    for (int j = 0; j < 2; ++j) {
      int row = j * 32 + arow;                    // 0..63
      int sw = aslot ^ (row & 7);
      gload16(&A32[(size_t)(bm * 64 + row) * DM + ks * 32 + sw * 4],
              &Asf[buf][row][aslot * 4]);
    }
    // B: 512 slot-units / 256 threads = 2 gloads
    #pragma unroll
    for (int j = 0; j < 2; ++j) {
      int row = j * 64 + brow;                    // 0..127
      int sw = bslot ^ ((row >> 1) & 3);
      gload16(&Bt[(size_t)(bn * 128 + row) * DM + ks * 32 + sw * 8],
              &Bs[buf][row][bslot * 8]);
    }
  };
  auto compute = [&](int buf) {
    bf16x8 a[2], b[4];
    #pragma unroll
    for (int m = 0; m < 2; ++m) {
      int row = wr * 32 + m * 16 + i16;
      int x = row & 7;
      float4 lo = *(const float4*)&Asf[buf][row][((g * 2) ^ x) * 4];
      float4 hi = *(const float4*)&Asf[buf][row][((g * 2 + 1) ^ x) * 4];
      union { unsigned short u[8]; bf16x8 v; } pk;
      pk.u[0] = b16(lo.x); pk.u[1] = b16(lo.y);
      pk.u[2] = b16(lo.z); pk.u[3] = b16(lo.w);
      pk.u[4] = b16(hi.x); pk.u[5] = b16(hi.y);
      pk.u[6] = b16(hi.z); pk.u[7] = b16(hi.w);
      a[m] = pk.v;
    }
    #pragma unroll
    for (int n = 0; n < 4; ++n) {
      int row = wc * 64 + n * 16 + i16;
      int sl = g ^ ((row >> 1) & 3);
      b[n] = *(const bf16x8*)&Bs[buf][row][sl * 8];
    }
    #pragma unroll
    for (int m = 0; m < 2; ++m)
      #pragma unroll
      for (int n = 0; n < 4; ++n)
        acc[m][n] = MFMA16(a[m], b[n], acc[m][n]);
  };

  stage(0, 0);
  __syncthreads();
  int cur = 0;
  #pragma unroll 1
  for (int ks = 0; ks < DM / 32; ++ks) {
    if (ks + 1 < DM / 32) stage(ks + 1, cur ^ 1);
    compute(cur);
    __syncthreads();
    cur ^= 1;
  }

  #pragma unroll
  for (int m = 0; m < 2; ++m) {
    #pragma unroll
    for (int n = 0; n < 4; ++n) {
      #pragma unroll
      for (int r = 0; r < 4; ++r) {
        int row = bm * 64 + wr * 32 + m * 16 + g * 4 + r;    // = b*2048+s
        int col = bn * 128 + wc * 64 + n * 16 + i16;         // 0..1023
        float v = (acc[m][n][r] + bias[col]) * scale;
        int b_ = row >> 11, s = row & 2047;
        int h = col >> 6, dd = col & 63;
        if (z != 2)   // Q,K head-major [B*H][S][64]
          O[(((size_t)(b_ * 16 + h)) * S_LEN + s) * DEPTH + dd] = f2b(v);
        else          // V transposed [B*H][64][S]
          O[(((size_t)(b_ * 16 + h)) * DEPTH + dd) * S_LEN + s] = f2b(v);
      }
    }
  }
}

// ---------------------------------------------------------------------------
// out projection (R13 structure)
// ---------------------------------------------------------------------------
__global__ __launch_bounds__(256, 4) void out_proj_k(
    const unsigned short* __restrict__ At, const unsigned short* __restrict__ Wto,
    const float* __restrict__ bo, float* __restrict__ out) {
  __shared__ __align__(16) unsigned short As[2][64][32];
  __shared__ __align__(16) unsigned short Bs[2][128][32];

  const int bm = blockIdx.x, bn = blockIdx.y;
  const int tid = threadIdx.x;
  const int wave = tid >> 6, lane = tid & 63;
  const int wr = wave >> 1, wc = wave & 1;
  const int g = lane >> 4, i16 = lane & 15;
  const int srow = tid >> 2, sslot = tid & 3;

  f32x4 acc[2][4] = {};

  auto stage = [&](int ks, int buf) {
    {
      int sw = sslot ^ ((srow >> 1) & 3);
      gload16(&At[(size_t)(bm * 64 + srow) * DM + ks * 32 + sw * 8],
              &As[buf][srow][sslot * 8]);
    }
    #pragma unroll
    for (int rnd = 0; rnd < 2; ++rnd) {
      int row = rnd * 64 + srow;
      int sw = sslot ^ ((row >> 1) & 3);
      gload16(&Wto[(size_t)(bn * 128 + row) * DM + ks * 32 + sw * 8],
              &Bs[buf][row][sslot * 8]);
    }
  };
  auto compute = [&](int buf) {
    bf16x8 a[2], b[4];
    #pragma unroll
    for (int m = 0; m < 2; ++m) {
      int row = wr * 32 + m * 16 + i16;
      int sl = g ^ ((row >> 1) & 3);
      a[m] = *(const bf16x8*)&As[buf][row][sl * 8];
    }
    #pragma unroll
    for (int n = 0; n < 4; ++n) {
      int row = wc * 64 + n * 16 + i16;
      int sl = g ^ ((row >> 1) & 3);
      b[n] = *(const bf16x8*)&Bs[buf][row][sl * 8];
    }
    #pragma unroll
    for (int m = 0; m < 2; ++m)
      #pragma unroll
      for (int n = 0; n < 4; ++n)
        acc[m][n] = MFMA16(a[m], b[n], acc[m][n]);
  };

  stage(0, 0);
  __syncthreads();
  int cur = 0;
  #pragma unroll 1
  for (int ks = 0; ks < DM / 32; ++ks) {
    if (ks + 1 < DM / 32) stage(ks + 1, cur ^ 1);
    compute(cur);
    __syncthreads();
    cur ^= 1;
  }

  #pragma unroll
  for (int m = 0; m < 2; ++m) {
    #pragma unroll
    for (int n = 0; n < 4; ++n) {
      #pragma unroll
      for (int r = 0; r < 4; ++r) {
        int row = bm * 64 + wr * 32 + m * 16 + g * 4 + r;
        int col = bn * 128 + wc * 64 + n * 16 + i16;
        out[(size_t)row * DM + col] = acc[m][n][r] + bo[col];
      }
    }
  }
}

// ---------------------------------------------------------------------------
// Flash attention (R16, frozen): 512 blocks XCD-swizzled, 4 waves, QBLK=128,
// KVBLK=128 per barrier as two independent 64-halves.
// ---------------------------------------------------------------------------
__global__ __launch_bounds__(256) void attn_k(
    const unsigned short* __restrict__ Qh, const unsigned short* __restrict__ Kh,
    const unsigned short* __restrict__ Vt, unsigned short* __restrict__ Ob) {
  __shared__ unsigned short Ks[2][128][64];        // 32KB
  __shared__ unsigned short Vs[2][64][128];        // 32KB (V^T rows d, cols kv)
  __shared__ unsigned short p_lds[4][2][16][64];   // [wave][qs][q16][kv64] 16KB

  const int linear = blockIdx.y * 16 + blockIdx.x;        // 0..511
  const int wg = (linear & 7) * 64 + (linear >> 3);       // XCD-bijective (512=8*64)
  const int qt = wg & 15, bh = wg >> 4;

  const int tid = threadIdx.x;
  const int wave = tid >> 6, lane = tid & 63;
  const int g = lane >> 4, i16 = lane & 15;

  const unsigned short* Q = Qh + (size_t)bh * S_LEN * DEPTH;
  const unsigned short* K = Kh + (size_t)bh * S_LEN * DEPTH;
  const unsigned short* V = Vt + (size_t)bh * DEPTH * S_LEN;   // V^T [64][2048]

  const int ksr = tid >> 3, kss = tid & 7;         // K staging
  const int vsr = tid >> 4, vss = tid & 15;        // V staging

  const int qbase = qt * 128 + wave * 32;
  bf16x8 qa[2][2];
  #pragma unroll
  for (int qs = 0; qs < 2; ++qs) {
    qa[qs][0] = *(const bf16x8*)&Q[(size_t)(qbase + qs * 16 + i16) * DEPTH + g * 8];
    qa[qs][1] = *(const bf16x8*)&Q[(size_t)(qbase + qs * 16 + i16) * DEPTH + 32 + g * 8];
  }

  const short one_b = (short)0x3F80;               // bf16 1.0
  const bf16x8 ones = {one_b, one_b, one_b, one_b, one_b, one_b, one_b, one_b};

  f32x4 l_acc[2] = {};           // row sums per qs, r-indexed (q = g*4+r)
  f32x4 o[2][4] = {};            // o[qs][dt][r]

  auto stage = [&](int t, int buf) {
    const int kv = t * 128;
    #pragma unroll
    for (int j = 0; j < 4; ++j) {
      int kr = j * 32 + ksr;                        // 0..127
      int ksw = kss ^ (kr & 7);
      gload16(&K[(size_t)(kv + kr) * DEPTH + ksw * 8], &Ks[buf][kr][kss * 8]);
      int vr = j * 16 + vsr;                        // 0..63
      int vsw = vss ^ (vr & 7);
      gload16(&V[(size_t)vr * S_LEN + kv + vsw * 8], &Vs[buf][vr][vss * 8]);
    }
  };

  stage(0, 0);
  __syncthreads();

  int cur = 0;
  #pragma unroll 1
  for (int t128 = 0; t128 < 16; ++t128) {
    if (t128 + 1 < 16) stage(t128 + 1, cur ^ 1);

    #pragma unroll
    for (int h = 0; h < 2; ++h) {
      f32x4 sT[2][4];
      const f32x4 zero = {0.f, 0.f, 0.f, 0.f};
      __builtin_amdgcn_s_setprio(1);
      #pragma unroll
      for (int t = 0; t < 4; ++t) {
        int row = h * 64 + t * 16 + i16;
        int x = row & 7;
        bf16x8 k0 = *(const bf16x8*)&Ks[cur][row][(g ^ x) * 8];
        bf16x8 k1 = *(const bf16x8*)&Ks[cur][row][((4 + g) ^ x) * 8];
        #pragma unroll
        for (int qs = 0; qs < 2; ++qs) {
          f32x4 s = MFMA16(k0, qa[qs][0], zero);
          sT[qs][t] = MFMA16(k1, qa[qs][1], s);
        }
      }
      __builtin_amdgcn_s_setprio(0);

      wave_lds_fence();   // h=1: writes must not hoist above h=0's reads
      #pragma unroll
      for (int qs = 0; qs < 2; ++qs) {
        #pragma unroll
        for (int t = 0; t < 4; ++t) {
          ushort4 w;
          w.x = b16(EXP2(sT[qs][t][0]));
          w.y = b16(EXP2(sT[qs][t][1]));
          w.z = b16(EXP2(sT[qs][t][2]));
          w.w = b16(EXP2(sT[qs][t][3]));
          int idx = (((t * 2 + (g >> 1)) ^ (i16 & 7)) * 8) + (g & 1) * 4;
          *(ushort4*)&p_lds[wave][qs][i16][idx] = w;
        }
      }
      wave_lds_fence();
      bf16x8 pa0[2], pa1[2];
      #pragma unroll
      for (int qs = 0; qs < 2; ++qs) {
        pa0[qs] = *(const bf16x8*)&p_lds[wave][qs][i16][(g ^ (i16 & 7)) * 8];
        pa1[qs] = *(const bf16x8*)&p_lds[wave][qs][i16][((4 + g) ^ (i16 & 7)) * 8];
      }

      __builtin_amdgcn_s_setprio(1);
      #pragma unroll
      for (int dt = 0; dt < 4; ++dt) {
        int row = dt * 16 + i16;
        int x = row & 7;
        bf16x8 v0 = *(const bf16x8*)&Vs[cur][row][((h * 8 + g) ^ x) * 8];
        bf16x8 v1 = *(const bf16x8*)&Vs[cur][row][((h * 8 + 4 + g) ^ x) * 8];
        #pragma unroll
        for (int qs = 0; qs < 2; ++qs) {
          o[qs][dt] = MFMA16(pa0[qs], v0, o[qs][dt]);
          o[qs][dt] = MFMA16(pa1[qs], v1, o[qs][dt]);
        }
      }
      #pragma unroll
      for (int qs = 0; qs < 2; ++qs) {
        l_acc[qs] = MFMA16(pa0[qs], ones, l_acc[qs]);
        l_acc[qs] = MFMA16(pa1[qs], ones, l_acc[qs]);
      }
      __builtin_amdgcn_s_setprio(0);
    }

    __syncthreads();
    cur ^= 1;
  }

  const int b_ = bh >> 4, h_ = bh & 15;
  #pragma unroll
  for (int qs = 0; qs < 2; ++qs) {
    f32x4 rinv;
    #pragma unroll
    for (int r = 0; r < 4; ++r)
      rinv[r] = 1.0f / l_acc[qs][r];
    #pragma unroll
    for (int dt = 0; dt < 4; ++dt) {
      #pragma unroll
      for (int r = 0; r < 4; ++r) {
        int qrow = qbase + qs * 16 + g * 4 + r;
        float val = o[qs][dt][r] * rinv[r];
        Ob[((size_t)(b_ * S_LEN + qrow)) * DM + h_ * DEPTH + dt * 16 + i16] = f2b(val);
      }
    }
  }
}

extern "C" void kernel_launch(void* const* d_in, const int* in_sizes, int n_in,
                              void* d_out, int out_size, void* d_ws, size_t ws_size,
                              hipStream_t stream) {
  const float* q  = (const float*)d_in[0];
  const float* k  = (const float*)d_in[1];
  const float* v  = (const float*)d_in[2];
  const float* Wq = (const float*)d_in[3];
  const float* bq = (const float*)d_in[4];
  const float* Wk = (const float*)d_in[5];
  const float* bk = (const float*)d_in[6];
  const float* Wv = (const float*)d_in[7];
  const float* bv = (const float*)d_in[8];
  const float* Wo = (const float*)d_in[9];
  const float* bo = (const float*)d_in[10];
  float* out = (float*)d_out;

  // ws layout (bf16 elems): Qh(4M) Kh(4M) Vt(4M) At(4M) Wt(4M)
  const size_t HEAD_ELEMS = (size_t)2 * 16 * S_LEN * DEPTH;  // 4,194,304
  unsigned short* Qh = (unsigned short*)d_ws;
  unsigned short* Kh = Qh + HEAD_ELEMS;
  unsigned short* Vt = Kh + HEAD_ELEMS;
  unsigned short* At = Vt + HEAD_ELEMS;
  unsigned short* Wt = At + 3 * HEAD_ELEMS;       // 4 x 1,048,576

  dim3 blk(256);
  hipLaunchKernelGGL(prep_k, dim3(1024), blk, 0, stream, Wq, Wk, Wv, Wo, Wt);
  hipLaunchKernelGGL(proj_qkv_k, dim3(64, 8, 3), blk, 0, stream,
                     q, k, v, Wt, bq, bk, bv, Qh, Kh, Vt);
  hipLaunchKernelGGL(attn_k, dim3(16, 32), blk, 0, stream, Qh, Kh, Vt, At);
  hipLaunchKernelGGL(out_proj_k, dim3(64, 8), blk, 0, stream,
                     At, Wt + (size_t)3 * DM * DM, bo, out);
}

// Round 19
// 121.983 us; speedup vs baseline: 1.1025x; 1.1025x over previous
//
#include <hip/hip_runtime.h>
#include <hip/hip_bf16.h>
#include <stdint.h>

// MHA forward, B=2 S=2048 D=1024 H=16 depth=64.  [R17 best config, restored]
// Stage 0: prep — W->bf16 transposed Wt[n][k] ONLY (x read fp32 by proj)
// Stage 1: QKV proj: BM=128. A = raw fp32 x staged via global_load_lds (fp32
//          LDS tile, bf16 cvt on fragment read); B = bf16 Wt via gload_lds.
// Stage 2: flash attention QBLK=128/KVBLK=128 two-half (R16, frozen)
// Stage 3: output projection (BM=64, R13)

typedef __attribute__((ext_vector_type(8))) short bf16x8;
typedef __attribute__((ext_vector_type(4))) float f32x4;

#define MFMA16(a, b, c) __builtin_amdgcn_mfma_f32_16x16x32_bf16((a), (b), (c), 0, 0, 0)
#define EXP2(x) __builtin_amdgcn_exp2f(x)   // v_exp_f32 (2^x native)

static constexpr int S_LEN = 2048;
static constexpr int DM    = 1024;
static constexpr int DEPTH = 64;
static constexpr float QSCALE = 0.125f * 1.44269504088896340736f;  // 1/sqrt(64)*log2e

__device__ __forceinline__ unsigned short f2b(float f) {
  unsigned u = __float_as_uint(f);
  unsigned r = 0x7FFFu + ((u >> 16) & 1u);   // RNE
  return (unsigned short)((u + r) >> 16);
}

// native bf16 convert (compiler emits/fuses v_cvt_pk_bf16_f32)
__device__ __forceinline__ unsigned short b16(float f) {
  __hip_bfloat16 h = __float2bfloat16(f);
  union { __hip_bfloat16 h; unsigned short u; } c; c.h = h; return c.u;
}

// async global->LDS, 16B per lane; LDS dest must be lane-linear within wave.
__device__ __forceinline__ void gload16(const void* g, void* l) {
  __builtin_amdgcn_global_load_lds(
      (const __attribute__((address_space(1))) void*)g,
      (__attribute__((address_space(3))) void*)l, 16, 0, 0);
}

// Wave-level LDS ordering fence for intra-wave cross-lane exchange.
__device__ __forceinline__ void wave_lds_fence() {
  asm volatile("" ::: "memory");
  __builtin_amdgcn_sched_barrier(0);
}

// ---------------------------------------------------------------------------
// prep: Wt[w][n][k] = bf16(W[k][n]) for w in {q,k,v,o}. 64x64 LDS-tiled.
// ---------------------------------------------------------------------------
__global__ __launch_bounds__(256) void prep_k(
    const float* __restrict__ Wq, const float* __restrict__ Wk,
    const float* __restrict__ Wv, const float* __restrict__ Wo,
    unsigned short* __restrict__ Wt) {
  __shared__ unsigned short ts[64][68];
  const int bid = blockIdx.x;
  const int tid = threadIdx.x;
  const int w = bid >> 8, tile = bid & 255;
  const int tr = tile >> 4, tc = tile & 15;       // tr: k-tile, tc: n-tile
  const float* W = (w == 0) ? Wq : (w == 1) ? Wk : (w == 2) ? Wv : Wo;
  unsigned short* T = Wt + (size_t)w * DM * DM;
  const int kr = tid >> 4, nc = (tid & 15) * 4;
  #pragma unroll
  for (int j = 0; j < 4; ++j) {
    int k = tr * 64 + kr + j * 16;
    float4 v = *(const float4*)&W[(size_t)k * DM + tc * 64 + nc];
    ushort4 u; u.x = f2b(v.x); u.y = f2b(v.y); u.z = f2b(v.z); u.w = f2b(v.w);
    *(ushort4*)&ts[kr + j * 16][nc] = u;
  }
  __syncthreads();
  const int nr = tid >> 4, kc = (tid & 15) * 4;
  #pragma unroll
  for (int j = 0; j < 4; ++j) {
    int n = tc * 64 + nr + j * 16;
    ushort4 u;
    u.x = ts[kc + 0][nr + j * 16];
    u.y = ts[kc + 1][nr + j * 16];
    u.z = ts[kc + 2][nr + j * 16];
    u.w = ts[kc + 3][nr + j * 16];
    *(ushort4*)&T[(size_t)n * DM + tr * 64 + kc] = u;
  }
}

// ---------------------------------------------------------------------------
// QKV projection: C = x_z * Wt_z^T + bias_z. 128x128 tile, BK=32, 4 waves.
// A: fp32 staged DIRECTLY via global_load_lds into f32 LDS tile (8 16B slots
//    per row, slot ^= row&7); converted bf16 on fragment read (2x b128 + cvt).
// B: bf16 Wt via global_load_lds + XOR swizzle. LDS 48KB -> 3 blk/CU (=grid).
// NOTE: BM=64 variant refuted twice (R11, R18) — halves MFMA-per-barrier
// while per-K-step stall is constant. Keep BM=128.
// ---------------------------------------------------------------------------
__global__ __launch_bounds__(256, 4) void proj_qkv_k(
    const float* __restrict__ xq, const float* __restrict__ xk,
    const float* __restrict__ xv, const unsigned short* __restrict__ Wt,
    const float* __restrict__ bq, const float* __restrict__ bk, const float* __restrict__ bv,
    unsigned short* __restrict__ Qh, unsigned short* __restrict__ Kh,
    unsigned short* __restrict__ Vt) {
  __shared__ __align__(16) float Asf[2][128][32];
  __shared__ __align__(16) unsigned short Bs[2][128][32];

  const int z = blockIdx.z;
  const float* A32 = (z == 0) ? xq : (z == 1) ? xk : xv;
  const unsigned short* Bt = Wt + (size_t)z * DM * DM;
  const float* bias = (z == 0) ? bq : (z == 1) ? bk : bv;
  const float scale = (z == 0) ? QSCALE : 1.0f;
  unsigned short* O = (z == 0) ? Qh : (z == 1) ? Kh : Vt;

  const int bm = blockIdx.x, bn = blockIdx.y;
  const int tid = threadIdx.x;
  const int wave = tid >> 6, lane = tid & 63;
  const int wr = wave >> 1, wc = wave & 1;
  const int g = lane >> 4, i16 = lane & 15;
  const int srow = tid >> 2, sslot = tid & 3;     // B staging

  f32x4 acc[4][4] = {};

  auto stage = [&](int ks, int buf) {
    // A: 128 rows x 8 slots of 4 floats; idx = tid + j*256 -> lane-linear dest
    #pragma unroll
    for (int j = 0; j < 4; ++j) {
      int idx = tid + j * 256;
      int row = idx >> 3, slot = idx & 7;
      int sw = slot ^ (row & 7);
      gload16(&A32[(size_t)(bm * 128 + row) * DM + ks * 32 + sw * 4],
              &Asf[buf][row][slot * 4]);
    }
    // B: bf16, 128 rows x 4 slots of 8 bf16
    #pragma unroll
    for (int rnd = 0; rnd < 2; ++rnd) {
      int row = rnd * 64 + srow;
      int sw = sslot ^ ((row >> 1) & 3);
      gload16(&Bt[(size_t)(bn * 128 + row) * DM + ks * 32 + sw * 8],
              &Bs[buf][row][sslot * 8]);
    }
  };
  auto compute = [&](int buf) {
    bf16x8 a[4], b[4];
    #pragma unroll
    for (int m = 0; m < 4; ++m) {
      int row = wr * 64 + m * 16 + i16;
      int x = row & 7;
      float4 lo = *(const float4*)&Asf[buf][row][((g * 2) ^ x) * 4];
      float4 hi = *(const float4*)&Asf[buf][row][((g * 2 + 1) ^ x) * 4];
      union { unsigned short u[8]; bf16x8 v; } pk;
      pk.u[0] = b16(lo.x); pk.u[1] = b16(lo.y);
      pk.u[2] = b16(lo.z); pk.u[3] = b16(lo.w);
      pk.u[4] = b16(hi.x); pk.u[5] = b16(hi.y);
      pk.u[6] = b16(hi.z); pk.u[7] = b16(hi.w);
      a[m] = pk.v;
    }
    #pragma unroll
    for (int n = 0; n < 4; ++n) {
      int row = wc * 64 + n * 16 + i16;
      int sl = g ^ ((row >> 1) & 3);
      b[n] = *(const bf16x8*)&Bs[buf][row][sl * 8];
    }
    #pragma unroll
    for (int m = 0; m < 4; ++m)
      #pragma unroll
      for (int n = 0; n < 4; ++n)
        acc[m][n] = MFMA16(a[m], b[n], acc[m][n]);
  };

  stage(0, 0);
  __syncthreads();
  int cur = 0;
  #pragma unroll 1
  for (int ks = 0; ks < DM / 32; ++ks) {
    if (ks + 1 < DM / 32) stage(ks + 1, cur ^ 1);
    compute(cur);
    __syncthreads();
    cur ^= 1;
  }

  #pragma unroll
  for (int m = 0; m < 4; ++m) {
    #pragma unroll
    for (int n = 0; n < 4; ++n) {
      #pragma unroll
      for (int r = 0; r < 4; ++r) {
        int row = bm * 128 + wr * 64 + m * 16 + g * 4 + r;   // = b*2048+s
        int col = bn * 128 + wc * 64 + n * 16 + i16;         // 0..1023
        float v = (acc[m][n][r] + bias[col]) * scale;
        int b_ = row >> 11, s = row & 2047;
        int h = col >> 6, dd = col & 63;
        if (z != 2)   // Q,K head-major [B*H][S][64]
          O[(((size_t)(b_ * 16 + h)) * S_LEN + s) * DEPTH + dd] = f2b(v);
        else          // V transposed [B*H][64][S]
          O[(((size_t)(b_ * 16 + h)) * DEPTH + dd) * S_LEN + s] = f2b(v);
      }
    }
  }
}

// ---------------------------------------------------------------------------
// out projection (R13 structure)
// ---------------------------------------------------------------------------
__global__ __launch_bounds__(256, 4) void out_proj_k(
    const unsigned short* __restrict__ At, const unsigned short* __restrict__ Wto,
    const float* __restrict__ bo, float* __restrict__ out) {
  __shared__ __align__(16) unsigned short As[2][64][32];
  __shared__ __align__(16) unsigned short Bs[2][128][32];

  const int bm = blockIdx.x, bn = blockIdx.y;
  const int tid = threadIdx.x;
  const int wave = tid >> 6, lane = tid & 63;
  const int wr = wave >> 1, wc = wave & 1;
  const int g = lane >> 4, i16 = lane & 15;
  const int srow = tid >> 2, sslot = tid & 3;

  f32x4 acc[2][4] = {};

  auto stage = [&](int ks, int buf) {
    {
      int sw = sslot ^ ((srow >> 1) & 3);
      gload16(&At[(size_t)(bm * 64 + srow) * DM + ks * 32 + sw * 8],
              &As[buf][srow][sslot * 8]);
    }
    #pragma unroll
    for (int rnd = 0; rnd < 2; ++rnd) {
      int row = rnd * 64 + srow;
      int sw = sslot ^ ((row >> 1) & 3);
      gload16(&Wto[(size_t)(bn * 128 + row) * DM + ks * 32 + sw * 8],
              &Bs[buf][row][sslot * 8]);
    }
  };
  auto compute = [&](int buf) {
    bf16x8 a[2], b[4];
    #pragma unroll
    for (int m = 0; m < 2; ++m) {
      int row = wr * 32 + m * 16 + i16;
      int sl = g ^ ((row >> 1) & 3);
      a[m] = *(const bf16x8*)&As[buf][row][sl * 8];
    }
    #pragma unroll
    for (int n = 0; n < 4; ++n) {
      int row = wc * 64 + n * 16 + i16;
      int sl = g ^ ((row >> 1) & 3);
      b[n] = *(const bf16x8*)&Bs[buf][row][sl * 8];
    }
    #pragma unroll
    for (int m = 0; m < 2; ++m)
      #pragma unroll
      for (int n = 0; n < 4; ++n)
        acc[m][n] = MFMA16(a[m], b[n], acc[m][n]);
  };

  stage(0, 0);
  __syncthreads();
  int cur = 0;
  #pragma unroll 1
  for (int ks = 0; ks < DM / 32; ++ks) {
    if (ks + 1 < DM / 32) stage(ks + 1, cur ^ 1);
    compute(cur);
    __syncthreads();
    cur ^= 1;
  }

  #pragma unroll
  for (int m = 0; m < 2; ++m) {
    #pragma unroll
    for (int n = 0; n < 4; ++n) {
      #pragma unroll
      for (int r = 0; r < 4; ++r) {
        int row = bm * 64 + wr * 32 + m * 16 + g * 4 + r;
        int col = bn * 128 + wc * 64 + n * 16 + i16;
        out[(size_t)row * DM + col] = acc[m][n][r] + bo[col];
      }
    }
  }
}

// ---------------------------------------------------------------------------
// Flash attention (R16, frozen): 512 blocks XCD-swizzled, 4 waves, QBLK=128,
// KVBLK=128 per barrier as two independent 64-halves. gload_lds + XOR swizzle,
// double-buffered; p_lds reused across halves (fenced); no-max softmax;
// l via ones-B MFMA.
// ---------------------------------------------------------------------------
__global__ __launch_bounds__(256) void attn_k(
    const unsigned short* __restrict__ Qh, const unsigned short* __restrict__ Kh,
    const unsigned short* __restrict__ Vt, unsigned short* __restrict__ Ob) {
  __shared__ unsigned short Ks[2][128][64];        // 32KB
  __shared__ unsigned short Vs[2][64][128];        // 32KB (V^T rows d, cols kv)
  __shared__ unsigned short p_lds[4][2][16][64];   // [wave][qs][q16][kv64] 16KB

  const int linear = blockIdx.y * 16 + blockIdx.x;        // 0..511
  const int wg = (linear & 7) * 64 + (linear >> 3);       // XCD-bijective (512=8*64)
  const int qt = wg & 15, bh = wg >> 4;

  const int tid = threadIdx.x;
  const int wave = tid >> 6, lane = tid & 63;
  const int g = lane >> 4, i16 = lane & 15;

  const unsigned short* Q = Qh + (size_t)bh * S_LEN * DEPTH;
  const unsigned short* K = Kh + (size_t)bh * S_LEN * DEPTH;
  const unsigned short* V = Vt + (size_t)bh * DEPTH * S_LEN;   // V^T [64][2048]

  const int ksr = tid >> 3, kss = tid & 7;         // K staging
  const int vsr = tid >> 4, vss = tid & 15;        // V staging

  const int qbase = qt * 128 + wave * 32;
  bf16x8 qa[2][2];
  #pragma unroll
  for (int qs = 0; qs < 2; ++qs) {
    qa[qs][0] = *(const bf16x8*)&Q[(size_t)(qbase + qs * 16 + i16) * DEPTH + g * 8];
    qa[qs][1] = *(const bf16x8*)&Q[(size_t)(qbase + qs * 16 + i16) * DEPTH + 32 + g * 8];
  }

  const short one_b = (short)0x3F80;               // bf16 1.0
  const bf16x8 ones = {one_b, one_b, one_b, one_b, one_b, one_b, one_b, one_b};

  f32x4 l_acc[2] = {};           // row sums per qs, r-indexed (q = g*4+r)
  f32x4 o[2][4] = {};            // o[qs][dt][r]

  auto stage = [&](int t, int buf) {
    const int kv = t * 128;
    #pragma unroll
    for (int j = 0; j < 4; ++j) {
      int kr = j * 32 + ksr;                        // 0..127
      int ksw = kss ^ (kr & 7);
      gload16(&K[(size_t)(kv + kr) * DEPTH + ksw * 8], &Ks[buf][kr][kss * 8]);
      int vr = j * 16 + vsr;                        // 0..63
      int vsw = vss ^ (vr & 7);
      gload16(&V[(size_t)vr * S_LEN + kv + vsw * 8], &Vs[buf][vr][vss * 8]);
    }
  };

  stage(0, 0);
  __syncthreads();

  int cur = 0;
  #pragma unroll 1
  for (int t128 = 0; t128 < 16; ++t128) {
    if (t128 + 1 < 16) stage(t128 + 1, cur ^ 1);

    #pragma unroll
    for (int h = 0; h < 2; ++h) {
      f32x4 sT[2][4];
      const f32x4 zero = {0.f, 0.f, 0.f, 0.f};
      __builtin_amdgcn_s_setprio(1);
      #pragma unroll
      for (int t = 0; t < 4; ++t) {
        int row = h * 64 + t * 16 + i16;
        int x = row & 7;
        bf16x8 k0 = *(const bf16x8*)&Ks[cur][row][(g ^ x) * 8];
        bf16x8 k1 = *(const bf16x8*)&Ks[cur][row][((4 + g) ^ x) * 8];
        #pragma unroll
        for (int qs = 0; qs < 2; ++qs) {
          f32x4 s = MFMA16(k0, qa[qs][0], zero);
          sT[qs][t] = MFMA16(k1, qa[qs][1], s);
        }
      }
      __builtin_amdgcn_s_setprio(0);

      wave_lds_fence();   // h=1: writes must not hoist above h=0's reads
      #pragma unroll
      for (int qs = 0; qs < 2; ++qs) {
        #pragma unroll
        for (int t = 0; t < 4; ++t) {
          ushort4 w;
          w.x = b16(EXP2(sT[qs][t][0]));
          w.y = b16(EXP2(sT[qs][t][1]));
          w.z = b16(EXP2(sT[qs][t][2]));
          w.w = b16(EXP2(sT[qs][t][3]));
          int idx = (((t * 2 + (g >> 1)) ^ (i16 & 7)) * 8) + (g & 1) * 4;
          *(ushort4*)&p_lds[wave][qs][i16][idx] = w;
        }
      }
      wave_lds_fence();
      bf16x8 pa0[2], pa1[2];
      #pragma unroll
      for (int qs = 0; qs < 2; ++qs) {
        pa0[qs] = *(const bf16x8*)&p_lds[wave][qs][i16][(g ^ (i16 & 7)) * 8];
        pa1[qs] = *(const bf16x8*)&p_lds[wave][qs][i16][((4 + g) ^ (i16 & 7)) * 8];
      }

      __builtin_amdgcn_s_setprio(1);
      #pragma unroll
      for (int dt = 0; dt < 4; ++dt) {
        int row = dt * 16 + i16;
        int x = row & 7;
        bf16x8 v0 = *(const bf16x8*)&Vs[cur][row][((h * 8 + g) ^ x) * 8];
        bf16x8 v1 = *(const bf16x8*)&Vs[cur][row][((h * 8 + 4 + g) ^ x) * 8];
        #pragma unroll
        for (int qs = 0; qs < 2; ++qs) {
          o[qs][dt] = MFMA16(pa0[qs], v0, o[qs][dt]);
          o[qs][dt] = MFMA16(pa1[qs], v1, o[qs][dt]);
        }
      }
      #pragma unroll
      for (int qs = 0; qs < 2; ++qs) {
        l_acc[qs] = MFMA16(pa0[qs], ones, l_acc[qs]);
        l_acc[qs] = MFMA16(pa1[qs], ones, l_acc[qs]);
      }
      __builtin_amdgcn_s_setprio(0);
    }

    __syncthreads();
    cur ^= 1;
  }

  const int b_ = bh >> 4, h_ = bh & 15;
  #pragma unroll
  for (int qs = 0; qs < 2; ++qs) {
    f32x4 rinv;
    #pragma unroll
    for (int r = 0; r < 4; ++r)
      rinv[r] = 1.0f / l_acc[qs][r];
    #pragma unroll
    for (int dt = 0; dt < 4; ++dt) {
      #pragma unroll
      for (int r = 0; r < 4; ++r) {
        int qrow = qbase + qs * 16 + g * 4 + r;
        float val = o[qs][dt][r] * rinv[r];
        Ob[((size_t)(b_ * S_LEN + qrow)) * DM + h_ * DEPTH + dt * 16 + i16] = f2b(val);
      }
    }
  }
}

extern "C" void kernel_launch(void* const* d_in, const int* in_sizes, int n_in,
                              void* d_out, int out_size, void* d_ws, size_t ws_size,
                              hipStream_t stream) {
  const float* q  = (const float*)d_in[0];
  const float* k  = (const float*)d_in[1];
  const float* v  = (const float*)d_in[2];
  const float* Wq = (const float*)d_in[3];
  const float* bq = (const float*)d_in[4];
  const float* Wk = (const float*)d_in[5];
  const float* bk = (const float*)d_in[6];
  const float* Wv = (const float*)d_in[7];
  const float* bv = (const float*)d_in[8];
  const float* Wo = (const float*)d_in[9];
  const float* bo = (const float*)d_in[10];
  float* out = (float*)d_out;

  // ws layout (bf16 elems): Qh(4M) Kh(4M) Vt(4M) At(4M) Wt(4M)
  const size_t HEAD_ELEMS = (size_t)2 * 16 * S_LEN * DEPTH;  // 4,194,304
  unsigned short* Qh = (unsigned short*)d_ws;
  unsigned short* Kh = Qh + HEAD_ELEMS;
  unsigned short* Vt = Kh + HEAD_ELEMS;
  unsigned short* At = Vt + HEAD_ELEMS;
  unsigned short* Wt = At + 3 * HEAD_ELEMS;       // 4 x 1,048,576

  dim3 blk(256);
  hipLaunchKernelGGL(prep_k, dim3(1024), blk, 0, stream, Wq, Wk, Wv, Wo, Wt);
  hipLaunchKernelGGL(proj_qkv_k, dim3(32, 8, 3), blk, 0, stream,
                     q, k, v, Wt, bq, bk, bv, Qh, Kh, Vt);
  hipLaunchKernelGGL(attn_k, dim3(16, 32), blk, 0, stream, Qh, Kh, Vt, At);
  hipLaunchKernelGGL(out_proj_k, dim3(64, 8), blk, 0, stream,
                     At, Wt + (size_t)3 * DM * DM, bo, out);
}